// Round 15
// baseline (360.791 us; speedup 1.0000x reference)
//
#include <hip/hip_runtime.h>
#include <cstdint>
#include <cstddef>

typedef _Float16 half8 __attribute__((ext_vector_type(8)));
typedef float    f32x4 __attribute__((ext_vector_type(4)));

#define NBLK 512        // blocks for binning passes
#define BSHIFT 8        // bucket = dst >> 8  (256 nodes per bucket)

static __device__ __forceinline__ float4 ld4(const float* p) {
    return *reinterpret_cast<const float4*>(p);
}

static __device__ __forceinline__ void ld8h(const _Float16* p, float* f) {
    half8 v = *reinterpret_cast<const half8*>(p);
#pragma unroll
    for (int k = 0; k < 8; ++k) f[k] = (float)v[k];
}

// ---------- binned CSR build ----------
// staging entry: (src << 8) | (dst & 255)   [src < 2^17, bucket-local dst < 256]

__global__ __launch_bounds__(256)
void binA_count(const int* __restrict__ dst, int* __restrict__ cntM,
                int e, int nb, int tile) {
    __shared__ int lc[512];
    const int t = threadIdx.x, j = blockIdx.x;
    lc[t] = 0; lc[t + 256] = 0;
    __syncthreads();
    const int lo = j * tile;
    const int hi = min(e, lo + tile);
    const int4* d4 = (const int4*)(dst + lo);
    const int n4 = (hi - lo) >> 2;
    for (int i = t; i < n4; i += 256) {
        int4 q = d4[i];
        atomicAdd(&lc[q.x >> BSHIFT], 1);
        atomicAdd(&lc[q.y >> BSHIFT], 1);
        atomicAdd(&lc[q.z >> BSHIFT], 1);
        atomicAdd(&lc[q.w >> BSHIFT], 1);
    }
    __syncthreads();
    for (int b = t; b < nb; b += 256) cntM[b * NBLK + j] = lc[b];
}

__global__ __launch_bounds__(256)
void scan1_kernel(const int* __restrict__ cnt, int* __restrict__ blockSums, int n) {
    __shared__ int ts[256];
    const int t = threadIdx.x;
    const int base = blockIdx.x * 1024 + t * 4;
    int s = 0;
    if (base + 3 < n) {
        int4 q = *reinterpret_cast<const int4*>(cnt + base);
        s = q.x + q.y + q.z + q.w;
    } else {
#pragma unroll
        for (int j = 0; j < 4; ++j) if (base + j < n) s += cnt[base + j];
    }
    ts[t] = s;
    __syncthreads();
    for (int off = 128; off > 0; off >>= 1) {
        if (t < off) ts[t] += ts[t + off];
        __syncthreads();
    }
    if (t == 0) blockSums[blockIdx.x] = ts[0];
}

// merged: each block scans the (<=256) blockSums itself, then does its local scan
__global__ __launch_bounds__(256)
void scan2_kernel(const int* __restrict__ cnt, const int* __restrict__ blockSums,
                  int* __restrict__ outp, int n, int nb) {
    __shared__ int bs[256];
    __shared__ int ts[256];
    const int t = threadIdx.x;
    bs[t] = (t < nb) ? blockSums[t] : 0;
    __syncthreads();
    for (int off = 1; off < 256; off <<= 1) {
        int v = (t >= off) ? bs[t - off] : 0;
        __syncthreads();
        bs[t] += v;
        __syncthreads();
    }
    const int blockOffset = (blockIdx.x == 0) ? 0 : bs[blockIdx.x - 1];

    const int base = blockIdx.x * 1024 + t * 4;
    int v[4] = {0, 0, 0, 0};
    if (base + 3 < n) {
        int4 q = *reinterpret_cast<const int4*>(cnt + base);
        v[0] = q.x; v[1] = q.y; v[2] = q.z; v[3] = q.w;
    } else {
#pragma unroll
        for (int j = 0; j < 4; ++j) if (base + j < n) v[j] = cnt[base + j];
    }
    int s = v[0] + v[1] + v[2] + v[3];
    ts[t] = s;
    __syncthreads();
    for (int off = 1; off < 256; off <<= 1) {
        int x = (t >= off) ? ts[t - off] : 0;
        __syncthreads();
        ts[t] += x;
        __syncthreads();
    }
    int excl = blockOffset + ((t == 0) ? 0 : ts[t - 1]);
#pragma unroll
    for (int j = 0; j < 4; ++j) {
        if (base + j < n) outp[base + j] = excl;
        excl += v[j];
    }
}

__global__ __launch_bounds__(256)
void binA_place(const int* __restrict__ src, const int* __restrict__ dst,
                const int* __restrict__ offM, unsigned* __restrict__ staging,
                int e, int nb, int tile) {
    __shared__ int cur[512];
    const int t = threadIdx.x, j = blockIdx.x;
    for (int b = t; b < nb; b += 256) cur[b] = offM[b * NBLK + j];
    __syncthreads();
    const int lo = j * tile;
    const int hi = min(e, lo + tile);
    const int4* s4 = (const int4*)(src + lo);
    const int4* d4 = (const int4*)(dst + lo);
    const int n4 = (hi - lo) >> 2;
    for (int i = t; i < n4; i += 256) {
        int4 qs = s4[i];
        int4 qd = d4[i];
        int p0 = atomicAdd(&cur[qd.x >> BSHIFT], 1);
        staging[p0] = ((unsigned)qs.x << 8) | (unsigned)(qd.x & 255);
        int p1 = atomicAdd(&cur[qd.y >> BSHIFT], 1);
        staging[p1] = ((unsigned)qs.y << 8) | (unsigned)(qd.y & 255);
        int p2 = atomicAdd(&cur[qd.z >> BSHIFT], 1);
        staging[p2] = ((unsigned)qs.z << 8) | (unsigned)(qd.z & 255);
        int p3 = atomicAdd(&cur[qd.w >> BSHIFT], 1);
        staging[p3] = ((unsigned)qs.w << 8) | (unsigned)(qd.w & 255);
    }
}

// fused: per-bucket hist + scan -> rowptr/dinv, then scatter src-only rec
__global__ __launch_bounds__(256)
void bucket_build(const unsigned* __restrict__ staging, const int* __restrict__ offM,
                  int* __restrict__ rowptr, float* __restrict__ dinv,
                  int* __restrict__ rec, int n, int nb, int e) {
    __shared__ int lc[256];
    __shared__ int ls[256];
    __shared__ int cur[256];
    const int b = blockIdx.x, t = threadIdx.x;
    const int base = offM[b * NBLK];
    const int end  = (b + 1 < nb) ? offM[(b + 1) * NBLK] : e;
    const int d0 = b << BSHIFT;
    const int R  = min(n - d0, 256);
    lc[t] = 0;
    __syncthreads();
    for (int i = base + t; i < end; i += 256) atomicAdd(&lc[staging[i] & 255u], 1);
    __syncthreads();
    const int deg = lc[t];
    ls[t] = deg;
    __syncthreads();
    for (int off = 1; off < 256; off <<= 1) {
        int v = (t >= off) ? ls[t - off] : 0;
        __syncthreads();
        ls[t] += v;
        __syncthreads();
    }
    int excl = (t == 0) ? 0 : ls[t - 1];
    if (t < R) {
        rowptr[d0 + t] = base + excl;
        dinv[d0 + t]   = rsqrtf((float)(deg + 1));
    }
    cur[t] = base + excl;
    if (b == nb - 1 && t == 0) rowptr[n] = e;
    __syncthreads();
    for (int i = base + t; i < end; i += 256) {
        unsigned q = staging[i];
        int pos = atomicAdd(&cur[q & 255u], 1);
        rec[pos] = (int)(q >> 8);
    }
}

// ---------- MFMA GEMM ----------
// H16 is HALF-SLICE-MAJOR: [2][N][64] fp16 (slice s = features [s*64, s*64+64)).
// IN32=1: X row-major fp32; IN32=0: X half-slice-major fp16 (read nontemporally).
template<int IN32>
__global__ __launch_bounds__(256)
void gemm_mfma_kernel(const void* __restrict__ Xv, const float* __restrict__ W,
                      _Float16* __restrict__ H16, int n) {
    __shared__ _Float16 Wt[128][136];
    __shared__ _Float16 Sw[4][16][136];

    const int t = threadIdx.x;
#pragma unroll
    for (int j = 0; j < 16; ++j) {
        int i4 = t + 256 * j;
        int k  = i4 >> 5;
        int c4 = (i4 & 31) * 4;
        float4 v = ld4(W + (size_t)i4 * 4);
        Wt[c4 + 0][k] = (_Float16)v.x;
        Wt[c4 + 1][k] = (_Float16)v.y;
        Wt[c4 + 2][k] = (_Float16)v.z;
        Wt[c4 + 3][k] = (_Float16)v.w;
    }
    __syncthreads();

    const int wave = t >> 6;
    const int l    = t & 63;
    const int lr   = l & 15;
    const int lk   = l >> 4;
    const int rowA = blockIdx.x * 64 + wave * 16 + lr;

    half8 a[4];
#pragma unroll
    for (int ks = 0; ks < 4; ++ks) {
#pragma unroll
        for (int j = 0; j < 8; ++j) a[ks][j] = (_Float16)0.f;
    }
    if (rowA < n) {
        if (IN32) {
            const float* X = (const float*)Xv;
#pragma unroll
            for (int ks = 0; ks < 4; ++ks) {
                const float* p = X + (size_t)rowA * 128 + ks * 32 + lk * 8;
                float4 f0 = ld4(p);
                float4 f1 = ld4(p + 4);
                a[ks][0] = (_Float16)f0.x; a[ks][1] = (_Float16)f0.y;
                a[ks][2] = (_Float16)f0.z; a[ks][3] = (_Float16)f0.w;
                a[ks][4] = (_Float16)f1.x; a[ks][5] = (_Float16)f1.y;
                a[ks][6] = (_Float16)f1.z; a[ks][7] = (_Float16)f1.w;
            }
        } else {
            const _Float16* X = (const _Float16*)Xv;
#pragma unroll
            for (int ks = 0; ks < 4; ++ks) {
                // feature k = ks*32 + lk*8 + j  -> slice = ks>>1, within = (ks&1)*32 + lk*8 + j
                a[ks] = __builtin_nontemporal_load(reinterpret_cast<const half8*>(
                    X + ((size_t)(ks >> 1) * n + rowA) * 64 + (ks & 1) * 32 + lk * 8));
            }
        }
    }

#pragma unroll
    for (int tt = 0; tt < 8; ++tt) {
        f32x4 acc = {0.f, 0.f, 0.f, 0.f};
#pragma unroll
        for (int ks = 0; ks < 4; ++ks) {
            half8 b = *reinterpret_cast<const half8*>(&Wt[tt * 16 + lr][ks * 32 + lk * 8]);
            acc = __builtin_amdgcn_mfma_f32_16x16x32_f16(a[ks], b, acc, 0, 0, 0);
        }
#pragma unroll
        for (int r = 0; r < 4; ++r)
            Sw[wave][lk * 4 + r][tt * 16 + lr] = (_Float16)acc[r];
    }
    __syncthreads();

#pragma unroll
    for (int j = 0; j < 4; ++j) {
        int chunk = l + 64 * j;
        int r  = chunk >> 4;
        int c8 = chunk & 15;               // feature-8-group: features [c8*8, c8*8+8)
        int gr = blockIdx.x * 64 + wave * 16 + r;
        if (gr < n) {
            half8 v = *reinterpret_cast<const half8*>(&Sw[wave][r][c8 * 8]);
            *reinterpret_cast<half8*>(
                H16 + ((size_t)(c8 >> 3) * n + gr) * 64 + (c8 & 7) * 8) = v;
        }
    }
}

// ---------- gather: 2 feature-slices (blockIdx&1), lane-parallel shape, nt hints ----------
// 8 lanes per dst node x 8 features (16B); chunked lane-parallel rec+dinv load,
// shfl(.,8) broadcast, 4-way unroll. rec = nt load; output = nt store (keep L2 for h16).
__global__ __launch_bounds__(256)
void gather_kernel(const int* __restrict__ rowptr, const int* __restrict__ rec,
                   const float* __restrict__ dinv,
                   const _Float16* __restrict__ h16, const float* __restrict__ bias,
                   _Float16* __restrict__ outb, int n, int do_relu) {
    const int slice = blockIdx.x & 1;
    const int tile  = blockIdx.x >> 1;
    const int t     = threadIdx.x;
    const int node  = tile * 32 + (t >> 3);
    const int lane  = t & 7;
    const int fo    = lane * 8;
    if (node >= n) return;

    const size_t sb = (size_t)slice * n;   // slice base, in 64-half rows

    int rs = rowptr[node];
    int re = rowptr[node + 1];
    float di = dinv[node];

    float acc[8];
    {
        float f[8];
        ld8h(h16 + (sb + node) * 64 + fo, f);
        float c = di * di;
#pragma unroll
        for (int k = 0; k < 8; ++k) acc[k] = c * f[k];
    }

    for (int e0 = rs; e0 < re; e0 += 8) {
        int m = re - e0;
        if (m > 8) m = 8;
        int   sI = 0;
        float wI = 0.f;
        if (lane < m) {
            sI = __builtin_nontemporal_load(rec + e0 + lane);
            wI = dinv[sI] * di;
        }
        int j = 0;
        for (; j + 3 < m; j += 4) {
            int   s0 = __shfl(sI, j,     8);
            float w0 = __shfl(wI, j,     8);
            int   s1 = __shfl(sI, j + 1, 8);
            float w1 = __shfl(wI, j + 1, 8);
            int   s2 = __shfl(sI, j + 2, 8);
            float w2 = __shfl(wI, j + 2, 8);
            int   s3 = __shfl(sI, j + 3, 8);
            float w3 = __shfl(wI, j + 3, 8);
            float f0[8], f1[8], f2[8], f3[8];
            ld8h(h16 + (sb + s0) * 64 + fo, f0);
            ld8h(h16 + (sb + s1) * 64 + fo, f1);
            ld8h(h16 + (sb + s2) * 64 + fo, f2);
            ld8h(h16 + (sb + s3) * 64 + fo, f3);
#pragma unroll
            for (int k = 0; k < 8; ++k) {
                acc[k] = fmaf(w0, f0[k], acc[k]);
                acc[k] = fmaf(w1, f1[k], acc[k]);
                acc[k] = fmaf(w2, f2[k], acc[k]);
                acc[k] = fmaf(w3, f3[k], acc[k]);
            }
        }
        for (; j < m; ++j) {
            int   s0 = __shfl(sI, j, 8);
            float w0 = __shfl(wI, j, 8);
            float f0[8];
            ld8h(h16 + (sb + s0) * 64 + fo, f0);
#pragma unroll
            for (int k = 0; k < 8; ++k) acc[k] = fmaf(w0, f0[k], acc[k]);
        }
    }

    float4 b0 = ld4(bias + slice * 64 + fo);
    float4 b1 = ld4(bias + slice * 64 + fo + 4);
    acc[0] += b0.x; acc[1] += b0.y; acc[2] += b0.z; acc[3] += b0.w;
    acc[4] += b1.x; acc[5] += b1.y; acc[6] += b1.z; acc[7] += b1.w;
    if (do_relu) {
#pragma unroll
        for (int k = 0; k < 8; ++k) acc[k] = fmaxf(acc[k], 0.f);
    }
    half8 v;
#pragma unroll
    for (int k = 0; k < 8; ++k) v[k] = (_Float16)acc[k];
    __builtin_nontemporal_store(v, reinterpret_cast<half8*>(outb + (sb + node) * 64 + fo));
}

// ---------- fused pooling + classifier (half-slice-major input) ----------
__global__ __launch_bounds__(256)
void pool_final_kernel(const _Float16* __restrict__ h, const int* __restrict__ batch,
                       const float* __restrict__ Wl, const float* __restrict__ bl,
                       float* __restrict__ out, int n, int n_classes) {
    __shared__ f32x4 red[16][34];
    __shared__ float cpart[10][16];
    int g = blockIdx.x;
    int lo = 0, hi = n;
    while (lo < hi) { int mid = (lo + hi) >> 1; if (batch[mid] < g) lo = mid + 1; else hi = mid; }
    int start = lo;
    hi = n;
    while (lo < hi) { int mid = (lo + hi) >> 1; if (batch[mid] < g + 1) lo = mid + 1; else hi = mid; }
    int end = lo;

    const int t   = threadIdx.x;
    const int grp = t >> 4;
    const int ln  = t & 15;          // feature chunk [ln*8, ln*8+8) -> slice ln>>3, within (ln&7)*8

    float acc[8] = {0.f, 0.f, 0.f, 0.f, 0.f, 0.f, 0.f, 0.f};
    for (int i = start + grp; i < end; i += 16) {
        float f[8];
        ld8h(h + ((size_t)(ln >> 3) * n + i) * 64 + (ln & 7) * 8, f);
#pragma unroll
        for (int k = 0; k < 8; ++k) acc[k] += f[k];
    }
    red[grp][ln * 2]     = (f32x4){acc[0], acc[1], acc[2], acc[3]};
    red[grp][ln * 2 + 1] = (f32x4){acc[4], acc[5], acc[6], acc[7]};
    __syncthreads();
#pragma unroll
    for (int off = 8; off > 0; off >>= 1) {
        if (grp < off) {
            red[grp][ln * 2]     += red[grp + off][ln * 2];
            red[grp][ln * 2 + 1] += red[grp + off][ln * 2 + 1];
        }
        __syncthreads();
    }
    if (t < n_classes * 16) {
        const int c = t >> 4;
        float p = 0.f;
#pragma unroll
        for (int k = 0; k < 8; ++k) {
            int kk = ln * 8 + k;
            p = fmaf(red[0][kk >> 2][kk & 3], Wl[kk * n_classes + c], p);
        }
        cpart[c][ln] = p;
    }
    __syncthreads();
    if (t < n_classes) {
        float s = 0.f;
#pragma unroll
        for (int k = 0; k < 16; ++k) s += cpart[t][k];
        float cnt = fmaxf((float)(end - start), 1.0f);
        out[g * n_classes + t] = s / cnt + bl[t];
    }
}

extern "C" void kernel_launch(void* const* d_in, const int* in_sizes, int n_in,
                              void* d_out, int out_size, void* d_ws, size_t ws_size,
                              hipStream_t stream) {
    const float* x     = (const float*)d_in[0];
    const int*   ei    = (const int*)d_in[1];
    const int*   batch = (const int*)d_in[2];
    const float* W1 = (const float*)d_in[3];
    const float* b1 = (const float*)d_in[4];
    const float* W2 = (const float*)d_in[5];
    const float* b2 = (const float*)d_in[6];
    const float* W3 = (const float*)d_in[7];
    const float* b3 = (const float*)d_in[8];
    const float* Wl = (const float*)d_in[9];
    const float* bl = (const float*)d_in[10];
    float* out = (float*)d_out;

    const int N = in_sizes[0] / 128;
    const int E = in_sizes[1] / 2;
    const int C = 10;
    const int G = out_size / C;

    const int* srcI = ei;
    const int* dstI = ei + E;

    const int NB   = (N + 255) >> BSHIFT;
    const int M    = NB * NBLK;
    const int TILE = (((E + NBLK - 1) / NBLK) + 3) & ~3;   // multiple of 4 for int4 loads
    const int scanB = (M + 1023) / 1024;                   // <= 256 (needed by merged scan2)

    char* w = (char*)d_ws;
    size_t off = 0;
    auto alloc = [&](size_t bytes) -> void* {
        void* p = w + off;
        off = (off + bytes + 255) & ~(size_t)255;
        return p;
    };

    int*      rowptr    = (int*)alloc((size_t)(N + 1) * 4);
    float*    dinv      = (float*)alloc((size_t)N * 4);
    int*      rec       = (int*)alloc((size_t)E * 4);
    unsigned* staging   = (unsigned*)alloc((size_t)E * 4);
    int*      cntM      = (int*)alloc((size_t)M * 4);
    int*      offM      = (int*)alloc((size_t)M * 4);
    int*      blockSums = (int*)alloc((size_t)scanB * 4);
    _Float16* h16       = (_Float16*)alloc((size_t)N * 128 * 2);   // [2][N][64]
    _Float16* act16     = (_Float16*)alloc((size_t)N * 128 * 2);   // [2][N][64]

    // ---- binned CSR build (once) ----
    binA_count<<<NBLK, 256, 0, stream>>>(dstI, cntM, E, NB, TILE);
    scan1_kernel<<<scanB, 256, 0, stream>>>(cntM, blockSums, M);
    scan2_kernel<<<scanB, 256, 0, stream>>>(cntM, blockSums, offM, M, scanB);
    binA_place<<<NBLK, 256, 0, stream>>>(srcI, dstI, offM, staging, E, NB, TILE);
    bucket_build<<<NB, 256, 0, stream>>>(staging, offM, rowptr, dinv, rec, N, NB, E);

    const int gemmBlocks = (N + 63) / 64;
    const int gathBlocks = ((N + 31) / 32) * 2;

    // ---- layer 1 ----
    gemm_mfma_kernel<1><<<gemmBlocks, 256, 0, stream>>>(x, W1, h16, N);
    gather_kernel<<<gathBlocks, 256, 0, stream>>>(rowptr, rec, dinv, h16, b1, act16, N, 1);
    // ---- layer 2 ----
    gemm_mfma_kernel<0><<<gemmBlocks, 256, 0, stream>>>(act16, W2, h16, N);
    gather_kernel<<<gathBlocks, 256, 0, stream>>>(rowptr, rec, dinv, h16, b2, act16, N, 1);
    // ---- layer 3 ----
    gemm_mfma_kernel<0><<<gemmBlocks, 256, 0, stream>>>(act16, W3, h16, N);
    gather_kernel<<<gathBlocks, 256, 0, stream>>>(rowptr, rec, dinv, h16, b3, act16, N, 0);

    // ---- fused pool + classify ----
    pool_final_kernel<<<G, 256, 0, stream>>>(act16, batch, Wl, bl, out, N, C);
}

// Round 16
// 342.818 us; speedup vs baseline: 1.0524x; 1.0524x over previous
//
#include <hip/hip_runtime.h>
#include <cstdint>
#include <cstddef>

typedef _Float16 half8 __attribute__((ext_vector_type(8)));
typedef float    f32x4 __attribute__((ext_vector_type(4)));

#define NBLK 256        // blocks for binning passes (256 -> 16-entry segments, less RMW waste)
#define BSHIFT 8        // bucket = dst >> 8  (256 nodes per bucket)

static __device__ __forceinline__ float4 ld4(const float* p) {
    return *reinterpret_cast<const float4*>(p);
}

static __device__ __forceinline__ void ld8h(const _Float16* p, float* f) {
    half8 v = *reinterpret_cast<const half8*>(p);
#pragma unroll
    for (int k = 0; k < 8; ++k) f[k] = (float)v[k];
}

// ---------- binned CSR build ----------
// staging entry: (src << 8) | (dst & 255)   [src < 2^17, bucket-local dst < 256]

__global__ __launch_bounds__(256)
void binA_count(const int* __restrict__ dst, int* __restrict__ cntM,
                int e, int nb, int tile) {
    __shared__ int lc[512];
    const int t = threadIdx.x, j = blockIdx.x;
    lc[t] = 0; lc[t + 256] = 0;
    __syncthreads();
    const int lo = j * tile;
    const int hi = min(e, lo + tile);
    const int4* d4 = (const int4*)(dst + lo);
    const int n4 = (hi - lo) >> 2;
    for (int i = t; i < n4; i += 256) {
        int4 q = d4[i];
        atomicAdd(&lc[q.x >> BSHIFT], 1);
        atomicAdd(&lc[q.y >> BSHIFT], 1);
        atomicAdd(&lc[q.z >> BSHIFT], 1);
        atomicAdd(&lc[q.w >> BSHIFT], 1);
    }
    __syncthreads();
    for (int b = t; b < nb; b += 256) cntM[b * NBLK + j] = lc[b];
}

__global__ __launch_bounds__(256)
void scan1_kernel(const int* __restrict__ cnt, int* __restrict__ blockSums, int n) {
    __shared__ int ts[256];
    const int t = threadIdx.x;
    const int base = blockIdx.x * 1024 + t * 4;
    int s = 0;
    if (base + 3 < n) {
        int4 q = *reinterpret_cast<const int4*>(cnt + base);
        s = q.x + q.y + q.z + q.w;
    } else {
#pragma unroll
        for (int j = 0; j < 4; ++j) if (base + j < n) s += cnt[base + j];
    }
    ts[t] = s;
    __syncthreads();
    for (int off = 128; off > 0; off >>= 1) {
        if (t < off) ts[t] += ts[t + off];
        __syncthreads();
    }
    if (t == 0) blockSums[blockIdx.x] = ts[0];
}

// merged: each block scans the (<=256) blockSums itself, then does its local scan
__global__ __launch_bounds__(256)
void scan2_kernel(const int* __restrict__ cnt, const int* __restrict__ blockSums,
                  int* __restrict__ outp, int n, int nb) {
    __shared__ int bs[256];
    __shared__ int ts[256];
    const int t = threadIdx.x;
    bs[t] = (t < nb) ? blockSums[t] : 0;
    __syncthreads();
    for (int off = 1; off < 256; off <<= 1) {
        int v = (t >= off) ? bs[t - off] : 0;
        __syncthreads();
        bs[t] += v;
        __syncthreads();
    }
    const int blockOffset = (blockIdx.x == 0) ? 0 : bs[blockIdx.x - 1];

    const int base = blockIdx.x * 1024 + t * 4;
    int v[4] = {0, 0, 0, 0};
    if (base + 3 < n) {
        int4 q = *reinterpret_cast<const int4*>(cnt + base);
        v[0] = q.x; v[1] = q.y; v[2] = q.z; v[3] = q.w;
    } else {
#pragma unroll
        for (int j = 0; j < 4; ++j) if (base + j < n) v[j] = cnt[base + j];
    }
    int s = v[0] + v[1] + v[2] + v[3];
    ts[t] = s;
    __syncthreads();
    for (int off = 1; off < 256; off <<= 1) {
        int x = (t >= off) ? ts[t - off] : 0;
        __syncthreads();
        ts[t] += x;
        __syncthreads();
    }
    int excl = blockOffset + ((t == 0) ? 0 : ts[t - 1]);
#pragma unroll
    for (int j = 0; j < 4; ++j) {
        if (base + j < n) outp[base + j] = excl;
        excl += v[j];
    }
}

__global__ __launch_bounds__(256)
void binA_place(const int* __restrict__ src, const int* __restrict__ dst,
                const int* __restrict__ offM, unsigned* __restrict__ staging,
                int e, int nb, int tile) {
    __shared__ int cur[512];
    const int t = threadIdx.x, j = blockIdx.x;
    for (int b = t; b < nb; b += 256) cur[b] = offM[b * NBLK + j];
    __syncthreads();
    const int lo = j * tile;
    const int hi = min(e, lo + tile);
    const int4* s4 = (const int4*)(src + lo);
    const int4* d4 = (const int4*)(dst + lo);
    const int n4 = (hi - lo) >> 2;
    for (int i = t; i < n4; i += 256) {
        int4 qs = s4[i];
        int4 qd = d4[i];
        int p0 = atomicAdd(&cur[qd.x >> BSHIFT], 1);
        staging[p0] = ((unsigned)qs.x << 8) | (unsigned)(qd.x & 255);
        int p1 = atomicAdd(&cur[qd.y >> BSHIFT], 1);
        staging[p1] = ((unsigned)qs.y << 8) | (unsigned)(qd.y & 255);
        int p2 = atomicAdd(&cur[qd.z >> BSHIFT], 1);
        staging[p2] = ((unsigned)qs.z << 8) | (unsigned)(qd.z & 255);
        int p3 = atomicAdd(&cur[qd.w >> BSHIFT], 1);
        staging[p3] = ((unsigned)qs.w << 8) | (unsigned)(qd.w & 255);
    }
}

// fused: per-bucket hist + scan -> rowptr/dinv, then scatter src-only rec
__global__ __launch_bounds__(256)
void bucket_build(const unsigned* __restrict__ staging, const int* __restrict__ offM,
                  int* __restrict__ rowptr, float* __restrict__ dinv,
                  int* __restrict__ rec, int n, int nb, int e) {
    __shared__ int lc[256];
    __shared__ int ls[256];
    __shared__ int cur[256];
    const int b = blockIdx.x, t = threadIdx.x;
    const int base = offM[b * NBLK];
    const int end  = (b + 1 < nb) ? offM[(b + 1) * NBLK] : e;
    const int d0 = b << BSHIFT;
    const int R  = min(n - d0, 256);
    lc[t] = 0;
    __syncthreads();
    for (int i = base + t; i < end; i += 256) atomicAdd(&lc[staging[i] & 255u], 1);
    __syncthreads();
    const int deg = lc[t];
    ls[t] = deg;
    __syncthreads();
    for (int off = 1; off < 256; off <<= 1) {
        int v = (t >= off) ? ls[t - off] : 0;
        __syncthreads();
        ls[t] += v;
        __syncthreads();
    }
    int excl = (t == 0) ? 0 : ls[t - 1];
    if (t < R) {
        rowptr[d0 + t] = base + excl;
        dinv[d0 + t]   = rsqrtf((float)(deg + 1));
    }
    cur[t] = base + excl;
    if (b == nb - 1 && t == 0) rowptr[n] = e;
    __syncthreads();
    for (int i = base + t; i < end; i += 256) {
        unsigned q = staging[i];
        int pos = atomicAdd(&cur[q & 255u], 1);
        rec[pos] = (int)(q >> 8);
    }
}

// ---------- MFMA GEMM ----------
// H16 is HALF-SLICE-MAJOR: [2][N][64] fp16 (slice s = features [s*64, s*64+64)).
// IN32=1: X row-major fp32; IN32=0: X half-slice-major fp16.
template<int IN32>
__global__ __launch_bounds__(256)
void gemm_mfma_kernel(const void* __restrict__ Xv, const float* __restrict__ W,
                      _Float16* __restrict__ H16, int n) {
    __shared__ _Float16 Wt[128][136];
    __shared__ _Float16 Sw[4][16][136];

    const int t = threadIdx.x;
#pragma unroll
    for (int j = 0; j < 16; ++j) {
        int i4 = t + 256 * j;
        int k  = i4 >> 5;
        int c4 = (i4 & 31) * 4;
        float4 v = ld4(W + (size_t)i4 * 4);
        Wt[c4 + 0][k] = (_Float16)v.x;
        Wt[c4 + 1][k] = (_Float16)v.y;
        Wt[c4 + 2][k] = (_Float16)v.z;
        Wt[c4 + 3][k] = (_Float16)v.w;
    }
    __syncthreads();

    const int wave = t >> 6;
    const int l    = t & 63;
    const int lr   = l & 15;
    const int lk   = l >> 4;
    const int rowA = blockIdx.x * 64 + wave * 16 + lr;

    half8 a[4];
#pragma unroll
    for (int ks = 0; ks < 4; ++ks) {
#pragma unroll
        for (int j = 0; j < 8; ++j) a[ks][j] = (_Float16)0.f;
    }
    if (rowA < n) {
        if (IN32) {
            const float* X = (const float*)Xv;
#pragma unroll
            for (int ks = 0; ks < 4; ++ks) {
                const float* p = X + (size_t)rowA * 128 + ks * 32 + lk * 8;
                float4 f0 = ld4(p);
                float4 f1 = ld4(p + 4);
                a[ks][0] = (_Float16)f0.x; a[ks][1] = (_Float16)f0.y;
                a[ks][2] = (_Float16)f0.z; a[ks][3] = (_Float16)f0.w;
                a[ks][4] = (_Float16)f1.x; a[ks][5] = (_Float16)f1.y;
                a[ks][6] = (_Float16)f1.z; a[ks][7] = (_Float16)f1.w;
            }
        } else {
            const _Float16* X = (const _Float16*)Xv;
#pragma unroll
            for (int ks = 0; ks < 4; ++ks) {
                // feature k = ks*32 + lk*8 + j  -> slice = ks>>1, within = (ks&1)*32 + lk*8 + j
                a[ks] = *reinterpret_cast<const half8*>(
                    X + ((size_t)(ks >> 1) * n + rowA) * 64 + (ks & 1) * 32 + lk * 8);
            }
        }
    }

#pragma unroll
    for (int tt = 0; tt < 8; ++tt) {
        f32x4 acc = {0.f, 0.f, 0.f, 0.f};
#pragma unroll
        for (int ks = 0; ks < 4; ++ks) {
            half8 b = *reinterpret_cast<const half8*>(&Wt[tt * 16 + lr][ks * 32 + lk * 8]);
            acc = __builtin_amdgcn_mfma_f32_16x16x32_f16(a[ks], b, acc, 0, 0, 0);
        }
#pragma unroll
        for (int r = 0; r < 4; ++r)
            Sw[wave][lk * 4 + r][tt * 16 + lr] = (_Float16)acc[r];
    }
    __syncthreads();

#pragma unroll
    for (int j = 0; j < 4; ++j) {
        int chunk = l + 64 * j;
        int r  = chunk >> 4;
        int c8 = chunk & 15;               // feature-8-group: features [c8*8, c8*8+8)
        int gr = blockIdx.x * 64 + wave * 16 + r;
        if (gr < n) {
            half8 v = *reinterpret_cast<const half8*>(&Sw[wave][r][c8 * 8]);
            *reinterpret_cast<half8*>(
                H16 + ((size_t)(c8 >> 3) * n + gr) * 64 + (c8 & 7) * 8) = v;
        }
    }
}

// ---------- gather: 2 feature-slices (blockIdx&1), round-14 lane-parallel shape ----------
// 8 lanes per dst node x 8 features (16B); chunked lane-parallel rec+dinv load,
// shfl(.,8) broadcast, 4-way unroll. (nt hints removed: round-15 showed they regress.)
__global__ __launch_bounds__(256)
void gather_kernel(const int* __restrict__ rowptr, const int* __restrict__ rec,
                   const float* __restrict__ dinv,
                   const _Float16* __restrict__ h16, const float* __restrict__ bias,
                   _Float16* __restrict__ outb, int n, int do_relu) {
    const int slice = blockIdx.x & 1;
    const int tile  = blockIdx.x >> 1;
    const int t     = threadIdx.x;
    const int node  = tile * 32 + (t >> 3);
    const int lane  = t & 7;
    const int fo    = lane * 8;
    if (node >= n) return;

    const size_t sb = (size_t)slice * n;   // slice base, in 64-half rows

    int rs = rowptr[node];
    int re = rowptr[node + 1];
    float di = dinv[node];

    float acc[8];
    {
        float f[8];
        ld8h(h16 + (sb + node) * 64 + fo, f);
        float c = di * di;
#pragma unroll
        for (int k = 0; k < 8; ++k) acc[k] = c * f[k];
    }

    for (int e0 = rs; e0 < re; e0 += 8) {
        int m = re - e0;
        if (m > 8) m = 8;
        int   sI = 0;
        float wI = 0.f;
        if (lane < m) {
            sI = rec[e0 + lane];
            wI = dinv[sI] * di;
        }
        int j = 0;
        for (; j + 3 < m; j += 4) {
            int   s0 = __shfl(sI, j,     8);
            float w0 = __shfl(wI, j,     8);
            int   s1 = __shfl(sI, j + 1, 8);
            float w1 = __shfl(wI, j + 1, 8);
            int   s2 = __shfl(sI, j + 2, 8);
            float w2 = __shfl(wI, j + 2, 8);
            int   s3 = __shfl(sI, j + 3, 8);
            float w3 = __shfl(wI, j + 3, 8);
            float f0[8], f1[8], f2[8], f3[8];
            ld8h(h16 + (sb + s0) * 64 + fo, f0);
            ld8h(h16 + (sb + s1) * 64 + fo, f1);
            ld8h(h16 + (sb + s2) * 64 + fo, f2);
            ld8h(h16 + (sb + s3) * 64 + fo, f3);
#pragma unroll
            for (int k = 0; k < 8; ++k) {
                acc[k] = fmaf(w0, f0[k], acc[k]);
                acc[k] = fmaf(w1, f1[k], acc[k]);
                acc[k] = fmaf(w2, f2[k], acc[k]);
                acc[k] = fmaf(w3, f3[k], acc[k]);
            }
        }
        for (; j < m; ++j) {
            int   s0 = __shfl(sI, j, 8);
            float w0 = __shfl(wI, j, 8);
            float f0[8];
            ld8h(h16 + (sb + s0) * 64 + fo, f0);
#pragma unroll
            for (int k = 0; k < 8; ++k) acc[k] = fmaf(w0, f0[k], acc[k]);
        }
    }

    float4 b0 = ld4(bias + slice * 64 + fo);
    float4 b1 = ld4(bias + slice * 64 + fo + 4);
    acc[0] += b0.x; acc[1] += b0.y; acc[2] += b0.z; acc[3] += b0.w;
    acc[4] += b1.x; acc[5] += b1.y; acc[6] += b1.z; acc[7] += b1.w;
    if (do_relu) {
#pragma unroll
        for (int k = 0; k < 8; ++k) acc[k] = fmaxf(acc[k], 0.f);
    }
    half8 v;
#pragma unroll
    for (int k = 0; k < 8; ++k) v[k] = (_Float16)acc[k];
    *reinterpret_cast<half8*>(outb + (sb + node) * 64 + fo) = v;
}

// ---------- fused pooling + classifier (half-slice-major input) ----------
__global__ __launch_bounds__(256)
void pool_final_kernel(const _Float16* __restrict__ h, const int* __restrict__ batch,
                       const float* __restrict__ Wl, const float* __restrict__ bl,
                       float* __restrict__ out, int n, int n_classes) {
    __shared__ f32x4 red[16][34];
    __shared__ float cpart[10][16];
    int g = blockIdx.x;
    int lo = 0, hi = n;
    while (lo < hi) { int mid = (lo + hi) >> 1; if (batch[mid] < g) lo = mid + 1; else hi = mid; }
    int start = lo;
    hi = n;
    while (lo < hi) { int mid = (lo + hi) >> 1; if (batch[mid] < g + 1) lo = mid + 1; else hi = mid; }
    int end = lo;

    const int t   = threadIdx.x;
    const int grp = t >> 4;
    const int ln  = t & 15;          // feature chunk [ln*8, ln*8+8) -> slice ln>>3, within (ln&7)*8

    float acc[8] = {0.f, 0.f, 0.f, 0.f, 0.f, 0.f, 0.f, 0.f};
    for (int i = start + grp; i < end; i += 16) {
        float f[8];
        ld8h(h + ((size_t)(ln >> 3) * n + i) * 64 + (ln & 7) * 8, f);
#pragma unroll
        for (int k = 0; k < 8; ++k) acc[k] += f[k];
    }
    red[grp][ln * 2]     = (f32x4){acc[0], acc[1], acc[2], acc[3]};
    red[grp][ln * 2 + 1] = (f32x4){acc[4], acc[5], acc[6], acc[7]};
    __syncthreads();
#pragma unroll
    for (int off = 8; off > 0; off >>= 1) {
        if (grp < off) {
            red[grp][ln * 2]     += red[grp + off][ln * 2];
            red[grp][ln * 2 + 1] += red[grp + off][ln * 2 + 1];
        }
        __syncthreads();
    }
    if (t < n_classes * 16) {
        const int c = t >> 4;
        float p = 0.f;
#pragma unroll
        for (int k = 0; k < 8; ++k) {
            int kk = ln * 8 + k;
            p = fmaf(red[0][kk >> 2][kk & 3], Wl[kk * n_classes + c], p);
        }
        cpart[c][ln] = p;
    }
    __syncthreads();
    if (t < n_classes) {
        float s = 0.f;
#pragma unroll
        for (int k = 0; k < 16; ++k) s += cpart[t][k];
        float cnt = fmaxf((float)(end - start), 1.0f);
        out[g * n_classes + t] = s / cnt + bl[t];
    }
}

extern "C" void kernel_launch(void* const* d_in, const int* in_sizes, int n_in,
                              void* d_out, int out_size, void* d_ws, size_t ws_size,
                              hipStream_t stream) {
    const float* x     = (const float*)d_in[0];
    const int*   ei    = (const int*)d_in[1];
    const int*   batch = (const int*)d_in[2];
    const float* W1 = (const float*)d_in[3];
    const float* b1 = (const float*)d_in[4];
    const float* W2 = (const float*)d_in[5];
    const float* b2 = (const float*)d_in[6];
    const float* W3 = (const float*)d_in[7];
    const float* b3 = (const float*)d_in[8];
    const float* Wl = (const float*)d_in[9];
    const float* bl = (const float*)d_in[10];
    float* out = (float*)d_out;

    const int N = in_sizes[0] / 128;
    const int E = in_sizes[1] / 2;
    const int C = 10;
    const int G = out_size / C;

    const int* srcI = ei;
    const int* dstI = ei + E;

    const int NB   = (N + 255) >> BSHIFT;
    const int M    = NB * NBLK;
    const int TILE = (((E + NBLK - 1) / NBLK) + 3) & ~3;   // multiple of 4 for int4 loads
    const int scanB = (M + 1023) / 1024;                   // <= 256 (needed by merged scan2)

    char* w = (char*)d_ws;
    size_t off = 0;
    auto alloc = [&](size_t bytes) -> void* {
        void* p = w + off;
        off = (off + bytes + 255) & ~(size_t)255;
        return p;
    };

    int*      rowptr    = (int*)alloc((size_t)(N + 1) * 4);
    float*    dinv      = (float*)alloc((size_t)N * 4);
    int*      rec       = (int*)alloc((size_t)E * 4);
    unsigned* staging   = (unsigned*)alloc((size_t)E * 4);
    int*      cntM      = (int*)alloc((size_t)M * 4);
    int*      offM      = (int*)alloc((size_t)M * 4);
    int*      blockSums = (int*)alloc((size_t)scanB * 4);
    _Float16* h16       = (_Float16*)alloc((size_t)N * 128 * 2);   // [2][N][64]
    _Float16* act16     = (_Float16*)alloc((size_t)N * 128 * 2);   // [2][N][64]

    // ---- binned CSR build (once) ----
    binA_count<<<NBLK, 256, 0, stream>>>(dstI, cntM, E, NB, TILE);
    scan1_kernel<<<scanB, 256, 0, stream>>>(cntM, blockSums, M);
    scan2_kernel<<<scanB, 256, 0, stream>>>(cntM, blockSums, offM, M, scanB);
    binA_place<<<NBLK, 256, 0, stream>>>(srcI, dstI, offM, staging, E, NB, TILE);
    bucket_build<<<NB, 256, 0, stream>>>(staging, offM, rowptr, dinv, rec, N, NB, E);

    const int gemmBlocks = (N + 63) / 64;
    const int gathBlocks = ((N + 31) / 32) * 2;

    // ---- layer 1 ----
    gemm_mfma_kernel<1><<<gemmBlocks, 256, 0, stream>>>(x, W1, h16, N);
    gather_kernel<<<gathBlocks, 256, 0, stream>>>(rowptr, rec, dinv, h16, b1, act16, N, 1);
    // ---- layer 2 ----
    gemm_mfma_kernel<0><<<gemmBlocks, 256, 0, stream>>>(act16, W2, h16, N);
    gather_kernel<<<gathBlocks, 256, 0, stream>>>(rowptr, rec, dinv, h16, b2, act16, N, 1);
    // ---- layer 3 ----
    gemm_mfma_kernel<0><<<gemmBlocks, 256, 0, stream>>>(act16, W3, h16, N);
    gather_kernel<<<gathBlocks, 256, 0, stream>>>(rowptr, rec, dinv, h16, b3, act16, N, 0);

    // ---- fused pool + classify ----
    pool_final_kernel<<<G, 256, 0, stream>>>(act16, batch, Wl, bl, out, N, C);
}